// Round 1
// 98.669 us; speedup vs baseline: 1.0299x; 1.0299x over previous
//
#include <hip/hip_runtime.h>

// VQ nearest-neighbor via f16-split MFMA. N=65536 queries, DIM=64, K=1024.
// v = dot(z,c) - csq[k]/2; argmax_k v  ==  argmin_k ||z-c||^2.
// 2-term f16 split (absmax=0 verified): dot ~= zh.ch + 2^-11(zh.cl'+zl'.ch).
//
// Round-6 changes vs round 5 (101.6 us):
//  * prep_kernel: was 4 blocks (4 CUs!) with 256B-strided 16B reads
//    (~4x line overfetch). Now thread-per-(code,kt,quad): 8192 threads /
//    32 blocks, fully coalesced 32B/thread reads, csq via shfl_xor
//    butterfly over the 8 sub-threads of each code. Predict ~10 us -> ~1.5 us.
//  * vq_mfma K-loop: explicit 1-ahead register-rotate prefetch of the 4
//    B-fragments (global, ~200cy L2) and the scsqn value (ds_read, ~120cy)
//    so latency hides under the previous iteration's 24 MFMAs; the loads
//    no longer sit directly in front of their consuming MFMA chain.
//  * s_setprio(1) around the MFMA+argmax cluster: K-loop waves are
//    barrier-free/independent (the regime where setprio measured +4-7%).

typedef _Float16 half8 __attribute__((ext_vector_type(8)));
typedef float float4v __attribute__((ext_vector_type(4)));

constexpr int KCODES = 1024;
constexpr int DIM = 64;
constexpr int BLOCK = 256;

// d_ws layout
constexpr size_t WS_CSQN = 0;      // 1024 f32 (-csq/2)            = 4 KB
constexpr size_t WS_CBF = 4096;    // fragment-ordered split cb f16 = 256 KB

// Fragment-ordered split codebook:
// cbf[((t*2+kt)*2+hl)*512 + lane*8 + j], lane = quad*16+m, code = t*16+m,
// dim = kt*32 + quad*8 + j. hl=0: f16 high part; hl=1: residual * 2^11.
//
// Thread g handles (code k = g>>3, kt = (g>>2)&1, quad = g&3): loads 8
// CONSECUTIVE floats (coalesced), writes one h8 + one l8 fragment (16 B
// each), reduces csq across the 8 sub-threads via shfl (subs are the low
// 3 lane bits, so xor 1/2/4 stays in-wave).
__global__ __launch_bounds__(BLOCK) void prep_kernel(
    const float* __restrict__ cb, _Float16* __restrict__ cbf,
    float* __restrict__ csqn) {
  const int g = blockIdx.x * BLOCK + threadIdx.x;  // grid 32 x 256 = 8192
  const int k = g >> 3, sub = g & 7;
  const int kt = sub >> 2, quad = sub & 3;
  const int t = k >> 4, m = k & 15;

  const float* src = cb + (size_t)k * DIM + kt * 32 + quad * 8;
  const float4 p0 = ((const float4*)src)[0];
  const float4 p1 = ((const float4*)src)[1];
  const float x[8] = {p0.x, p0.y, p0.z, p0.w, p1.x, p1.y, p1.z, p1.w};

  half8 h8, l8;
  float s = 0.f;
#pragma unroll
  for (int j = 0; j < 8; ++j) {
    s = fmaf(x[j], x[j], s);
    const _Float16 h = (_Float16)x[j];
    h8[j] = h;
    l8[j] = (_Float16)((x[j] - (float)h) * 2048.0f);
  }
  // Sum csq over the 8 threads of this code (tree sum, >= old accuracy).
  s += __shfl_xor(s, 1);
  s += __shfl_xor(s, 2);
  s += __shfl_xor(s, 4);
  if (sub == 0) csqn[k] = -0.5f * s;

  const int lane8 = quad * 16 + m;
  _Float16* dst = cbf + (size_t)((t * 2 + kt) * 2) * 512 + lane8 * 8;
  *(half8*)(dst) = h8;        // hl = 0
  *(half8*)(dst + 512) = l8;  // hl = 1
}

// Block = 256 thr = 4 waves = 2 query-groups (64 q each) x 2 K-halves.
__global__ __launch_bounds__(BLOCK, 2) void vq_mfma(
    const float* __restrict__ z, const float4* __restrict__ cb4,
    const _Float16* __restrict__ cbf, const float* __restrict__ csqn_g,
    float4* __restrict__ out4) {
  __shared__ float scsqn[KCODES];
  __shared__ float rv[2][128];
  __shared__ int rk[2][128];
  __shared__ int sidx[128];

  const int tid = threadIdx.x;
  const int lane = tid & 63;
  const int wave = tid >> 6;
  const int qg = wave & 1;    // query group (64 queries)
  const int kh = wave >> 1;   // K half (512 codes)
  const int m = lane & 15;
  const int quad = lane >> 4;

  ((float4*)scsqn)[tid] = ((const float4*)csqn_g)[tid];

  // B base: this wave's K-half, fragment-ordered -> contiguous 1 KB loads.
  const _Float16* bbase = cbf + (size_t)kh * 65536 + lane * 8;

  // Issue tile-0 B loads before the A-fragment build so they are in
  // flight under the A conversion VALU work.
  half8 nbh0 = *(const half8*)(bbase);
  half8 nbl0 = *(const half8*)(bbase + 512);
  half8 nbh1 = *(const half8*)(bbase + 1024);
  half8 nbl1 = *(const half8*)(bbase + 1536);

  // A-fragments: 4 qtiles x 2 ktiles, h + l. A[m][k=quad*8+j].
  const int qbase = blockIdx.x * 128 + qg * 64;
  half8 ah[4][2], al[4][2];
#pragma unroll
  for (int qt = 0; qt < 4; ++qt) {
    const float* zr = z + (size_t)(qbase + qt * 16 + m) * DIM + quad * 8;
#pragma unroll
    for (int kt = 0; kt < 2; ++kt) {
      const float4 p0 = ((const float4*)(zr + kt * 32))[0];
      const float4 p1 = ((const float4*)(zr + kt * 32))[1];
      const float zf[8] = {p0.x, p0.y, p0.z, p0.w, p1.x, p1.y, p1.z, p1.w};
#pragma unroll
      for (int j = 0; j < 8; ++j) {
        const _Float16 h = (_Float16)zf[j];
        ah[qt][kt][j] = h;
        al[qt][kt][j] = (_Float16)((zf[j] - (float)h) * 2048.0f);
      }
    }
  }

  __syncthreads();  // scsqn visible

  const float4v zvec = {0.f, 0.f, 0.f, 0.f};
  float best[4][4];
  int bestk[4][4];
#pragma unroll
  for (int qt = 0; qt < 4; ++qt)
#pragma unroll
    for (int r = 0; r < 4; ++r) { best[qt][r] = -3.402823466e38f; bestk[qt][r] = 0; }

  float cnext = scsqn[kh * 512 + m];  // -csq/2 for tile 0, this lane's column

#pragma unroll 2
  for (int t = 0; t < 32; ++t) {
    // Rotate in the tile prefetched last iteration.
    const half8 bh0 = nbh0, bl0 = nbl0, bh1 = nbh1, bl1 = nbl1;
    const float c = cnext;

    // Prefetch tile t+1 (wraps to 0 at the end; harmless re-read).
    const int tn = (t + 1) & 31;
    const _Float16* pn = bbase + (size_t)tn * 2048;
    nbh0 = *(const half8*)(pn);
    nbl0 = *(const half8*)(pn + 512);
    nbh1 = *(const half8*)(pn + 1024);
    nbl1 = *(const half8*)(pn + 1536);
    cnext = scsqn[kh * 512 + tn * 16 + m];

    const int k16 = kh * 512 + t * 16 + m;  // this lane's code column
    const float4v cvec = {c, c, c, c};

    __builtin_amdgcn_s_setprio(1);
#pragma unroll
    for (int qt = 0; qt < 4; ++qt) {
      float4v am = __builtin_amdgcn_mfma_f32_16x16x32_f16(ah[qt][0], bh0, cvec, 0, 0, 0);
      am = __builtin_amdgcn_mfma_f32_16x16x32_f16(ah[qt][1], bh1, am, 0, 0, 0);
      float4v ax = __builtin_amdgcn_mfma_f32_16x16x32_f16(ah[qt][0], bl0, zvec, 0, 0, 0);
      ax = __builtin_amdgcn_mfma_f32_16x16x32_f16(ah[qt][1], bl1, ax, 0, 0, 0);
      ax = __builtin_amdgcn_mfma_f32_16x16x32_f16(al[qt][0], bh0, ax, 0, 0, 0);
      ax = __builtin_amdgcn_mfma_f32_16x16x32_f16(al[qt][1], bh1, ax, 0, 0, 0);
#pragma unroll
      for (int r = 0; r < 4; ++r) {
        const float v = fmaf(4.8828125e-4f, ax[r], am[r]);  // 2^-11
        // k ascending in t per lane: strict > keeps lowest-k maximum.
        if (v > best[qt][r]) { best[qt][r] = v; bestk[qt][r] = k16; }
      }
    }
    __builtin_amdgcn_s_setprio(0);
  }

  // Cross-lane argmax over the 16 cols (m) in each quad; ties -> lower k.
#pragma unroll
  for (int qt = 0; qt < 4; ++qt)
#pragma unroll
    for (int r = 0; r < 4; ++r) {
      float b = best[qt][r];
      int bk = bestk[qt][r];
#pragma unroll
      for (int s = 1; s < 16; s <<= 1) {
        const float ob = __shfl_xor(b, s);
        const int obk = __shfl_xor(bk, s);
        if (ob > b || (ob == b && obk < bk)) { b = ob; bk = obk; }
      }
      if (m == 0) {
        const int qb = qg * 64 + qt * 16 + quad * 4 + r;  // row = quad*4+r
        rv[kh][qb] = b;
        rk[kh][qb] = bk;
      }
    }
  __syncthreads();

  // Combine K-halves (strict >: ties -> half 0 = lower k).
  if (tid < 128) {
    const float v0 = rv[0][tid], v1 = rv[1][tid];
    sidx[tid] = (v1 > v0) ? rk[1][tid] : rk[0][tid];
  }
  __syncthreads();

  // Gather winning fp32 codebook rows; coalesced float4 writes.
  const size_t obase = (size_t)blockIdx.x * 128 * (DIM / 4);
#pragma unroll
  for (int f0 = 0; f0 < 128 * (DIM / 4); f0 += BLOCK) {
    const int f = f0 + tid;
    const int q = f >> 4, e = f & 15;
    out4[obase + f] = cb4[(size_t)sidx[q] * (DIM / 4) + e];
  }
}

extern "C" void kernel_launch(void* const* d_in, const int* in_sizes, int n_in,
                              void* d_out, int out_size, void* d_ws, size_t ws_size,
                              hipStream_t stream) {
  const float* z = (const float*)d_in[0];
  const float* cb = (const float*)d_in[1];
  char* ws = (char*)d_ws;
  float* csqn = (float*)(ws + WS_CSQN);
  _Float16* cbf = (_Float16*)(ws + WS_CBF);

  const int nq = in_sizes[0] / DIM;  // 65536
  prep_kernel<<<(KCODES * 8) / BLOCK, BLOCK, 0, stream>>>(cb, cbf, csqn);
  vq_mfma<<<nq / 128, BLOCK, 0, stream>>>(z, (const float4*)cb, cbf, csqn,
                                          (float4*)d_out);
}